// Round 3
// baseline (1085.077 us; speedup 1.0000x reference)
//
#include <hip/hip_runtime.h>

// Decision-tree traversal, fully LDS-resident inner loop.
//
// x:      [N, W] int32 in {0,1}  (N=250000, W=784 -> 784 MB)
// choices:[N_NODES=65537] int32 split feature per node (values < 784)
// preds:  [N_NODES] float32 leaf prediction (0.0/1.0)
// depth:  scalar int32 on device (=15)
// out:    [N] int32 (bool semantics 0/1)
//
// Evidence so far: baseline (direct gathers, 784 MB footprint) = 911 us;
// round-2 traverse (same gathers, 25 MB L3-resident footprint) = ~930 us.
// Footprint-independent => cost is per divergent-gather-instruction
// serialization in the vector-memory pipe, not cache misses. Fix: move ALL
// divergent inner-loop accesses to LDS (native divergent addressing):
//   - packed bits, word-major [25][256]  = 25.6 KB (bank = tid&31, 2-way free)
//   - choices levels 0..13 as u16        = 32.0 KB (nodes 0..16382)
//   - preds leaf-level bitmask           =  4.0 KB
//   total 61 KB static LDS -> 2 blocks/CU. Only level-14 choices remains a
//   global gather (1/sample instead of 31/sample).
//
// Pipeline: [pack_tables (tiny)] -> [pack bits, 784 MB stream] -> [traverse].
// Pack writes bits block-transposed [blk][word][row&255] so traverse staging
// is coalesced global + conflict-free ds_write.

#define WPR 25          // packed words per row for w=784
#define CH_LDS 16384    // u16 choices entries in LDS (levels 0..13)

// ------------------------------------------------ tiny: pack tree tables
__global__ __launch_bounds__(256) void pack_tables_kernel(
    const int*   __restrict__ choices,
    const float* __restrict__ preds,
    const int*   __restrict__ depth_p,
    unsigned short* __restrict__ ch16,      // [32768]
    unsigned*       __restrict__ predbits)  // [1024] words
{
    const int t = threadIdx.x;
    if (blockIdx.x < 128) {
        const int j = blockIdx.x * 256 + t;            // [0, 32768)
        ch16[j] = (unsigned short)choices[j];          // values < 784: lossless
    } else {
        const int b = (blockIdx.x - 128) * 256 + t;    // leaf bit [0, 32768)
        const int depth = *depth_p;
        const int base  = (1 << depth) - 1;
        const int count = 1 << depth;                  // <= 32768 if depth<=15
        const int v = (b < count) ? (preds[base + b] != 0.0f) : 0;
        const unsigned long long m = __ballot(v != 0);
        const int lane = t & 63;
        if (lane < 2) {
            const int word = ((b >> 6) << 1) + lane;
            if (word < 1024)
                predbits[word] = (unsigned)(m >> (lane << 5));
        }
    }
}

// ------------------------------------------------ pack x -> bit matrix
// One wave packs 4 rows; coalesced 256B loads + __ballot. Output layout is
// block-transposed: word w of row r -> packed[(r>>8)*WPR*256 + w*256 + (r&255)].
__global__ __launch_bounds__(256) void pack_kernel(
    const int* __restrict__ x,
    unsigned*  __restrict__ packed,
    int n, int w)
{
    constexpr int NSEG = 12, TAIL = 16;                // w = 784
    const int  gtid = blockIdx.x * blockDim.x + threadIdx.x;
    const int  wave = gtid >> 6;
    const int  lane = gtid & 63;
    const long long row0 = (long long)wave * 4;

    #pragma unroll
    for (int rr = 0; rr < 4; ++rr) {
        const long long r = row0 + rr;
        if (r >= n) return;                            // wave-uniform
        const int* __restrict__ rowp = x + r * (long long)w;
        unsigned*  __restrict__ outp = packed + (r >> 8) * (WPR * 256) + (r & 255);

        #pragma unroll
        for (int seg = 0; seg < NSEG; ++seg) {
            const int v = rowp[(seg << 6) + lane];             // coalesced 256B
            const unsigned long long m = __ballot(v != 0);
            if (lane < 2)
                outp[((seg << 1) + lane) * 256] = (unsigned)(m >> (lane << 5));
        }
        {   // tail: 16 features -> 1 word
            const int v = (lane < TAIL) ? rowp[(NSEG << 6) + lane] : 0;
            const unsigned long long m = __ballot(v != 0);
            if (lane == 0)
                outp[(2 * NSEG) * 256] = (unsigned)m;
        }
    }
}

// ------------------------------------------------ traverse, LDS inner loop
__global__ __launch_bounds__(256) void traverse_lds_kernel(
    const unsigned*       __restrict__ packed,
    const unsigned short* __restrict__ ch16,
    const unsigned*       __restrict__ predbits,
    const int*            __restrict__ choices,
    const float*          __restrict__ preds,
    const int*            __restrict__ depth_p,
    int* __restrict__ out, int n)
{
    __shared__ unsigned short ch[CH_LDS];     // 32.0 KB  (levels 0..13)
    __shared__ unsigned bits[WPR * 256];      // 25.6 KB  word-major
    __shared__ unsigned pb[1024];             //  4.0 KB  leaf predictions

    const int tid = threadIdx.x;
    const long long blockRow0 = (long long)blockIdx.x * 256;
    const int depth = *depth_p;

    // stage choices (8192 u32 = 32 coalesced iters)
    {
        const unsigned* __restrict__ src = (const unsigned*)ch16;
        unsigned* dst = (unsigned*)ch;
        #pragma unroll
        for (int k = 0; k < 32; ++k)
            dst[k * 256 + tid] = src[k * 256 + tid];
    }
    // stage leaf bitmask
    #pragma unroll
    for (int k = 0; k < 4; ++k)
        pb[k * 256 + tid] = predbits[k * 256 + tid];
    // stage this block's bit rows (already block-transposed in ws: coalesced
    // global loads, conflict-free contiguous ds_writes)
    {
        const unsigned* __restrict__ src = packed + (long long)blockIdx.x * (WPR * 256);
        #pragma unroll
        for (int k = 0; k < WPR; ++k)
            bits[k * 256 + tid] = src[k * 256 + tid];
    }
    __syncthreads();

    const long long i = blockRow0 + tid;
    if (i >= n) return;

    int node = 0;
    for (int d = 0; d < depth; ++d) {
        // level uniform: d<=13 -> LDS u16; deeper -> global table
        const int c = (node < CH_LDS - 1) ? (int)ch[node] : choices[node];
        const unsigned wv = bits[(c >> 5) * 256 + tid];   // bank = tid&31
        node = (node << 1) + (int)((wv >> (c & 31)) & 1u) + 1;
    }

    if (depth <= 15) {
        const int idx = node - ((1 << depth) - 1);        // [0, 2^depth)
        out[i] = (int)((pb[idx >> 5] >> (idx & 31)) & 1u);
    } else {
        out[i] = (preds[node] != 0.0f) ? 1 : 0;           // generic fallback
    }
}

// ------------------------------------------------ fallback (baseline 911us)
__global__ __launch_bounds__(256) void direct_kernel(
    const int*   __restrict__ x,
    const int*   __restrict__ choices,
    const float* __restrict__ preds,
    const int*   __restrict__ depth_p,
    int*         __restrict__ out,
    int n, int w)
{
    const int i = blockIdx.x * blockDim.x + threadIdx.x;
    if (i >= n) return;
    const int depth = *depth_p;
    const int* __restrict__ row = x + (long long)i * (long long)w;
    int node = 0;
    for (int d = 0; d < depth; ++d) {
        const int c   = choices[node];
        const int bit = row[c];
        node = node * 2 + bit + 1;
    }
    out[i] = (preds[node] != 0.0f) ? 1 : 0;
}

extern "C" void kernel_launch(void* const* d_in, const int* in_sizes, int n_in,
                              void* d_out, int out_size, void* d_ws, size_t ws_size,
                              hipStream_t stream) {
    const int*   x       = (const int*)d_in[0];
    const int*   choices = (const int*)d_in[1];
    const float* preds   = (const float*)d_in[2];
    const int*   depth_p = (const int*)d_in[3];
    int*         out     = (int*)d_out;

    const int n = out_size;                 // 250000 samples
    const int w = in_sizes[0] / n;          // 784 features

    const long long nblk = (n + 255) / 256;
    const size_t bits_bytes = (size_t)nblk * WPR * 256 * sizeof(unsigned); // ~25 MB
    const size_t ch16_off   = (bits_bytes + 255) & ~(size_t)255;
    const size_t pb_off     = ch16_off + 32768 * sizeof(unsigned short);
    const size_t need       = pb_off + 1024 * sizeof(unsigned);

    if (w != 784 || ws_size < need) {
        const int block = 256;
        const int grid  = (n + block - 1) / block;
        direct_kernel<<<grid, block, 0, stream>>>(x, choices, preds, depth_p,
                                                  out, n, w);
        return;
    }

    unsigned*       packed   = (unsigned*)d_ws;
    unsigned short* ch16     = (unsigned short*)((char*)d_ws + ch16_off);
    unsigned*       predbits = (unsigned*)((char*)d_ws + pb_off);

    // 1) tiny table pack (independent of big pack)
    pack_tables_kernel<<<256, 256, 0, stream>>>(choices, preds, depth_p,
                                                ch16, predbits);
    // 2) bit-pack x (784 MB stream), one wave packs 4 rows
    {
        const long long waves = ((long long)n + 3) / 4;
        const long long grid  = (waves + 3) / 4;       // 4 waves/block
        pack_kernel<<<dim3((unsigned)grid), 256, 0, stream>>>(x, packed, n, w);
    }
    // 3) traversal with LDS-resident bits/choices/preds
    traverse_lds_kernel<<<dim3((unsigned)nblk), 256, 0, stream>>>(
        packed, ch16, predbits, choices, preds, depth_p, out, n);
}

// Round 4
// 1041.102 us; speedup vs baseline: 1.0422x; 1.0422x over previous
//
#include <hip/hip_runtime.h>

// Decision-tree traversal: vectorized bit-pack + LDS-resident traversal.
//
// x:      [N, W] int32 in {0,1}  (N=250000, W=784 -> 784 MB)
// choices:[N_NODES=65537] int32 split feature per node (values < 784)
// preds:  [N_NODES] float32 leaf prediction (0.0/1.0)
// depth:  scalar int32 on device (=15)
// out:    [N] int32 (bool 0/1)
//
// Attribution from R0-R3: the ballot-based pack kernel ran at ~0.8 TB/s
// (~1000 us) and dominated; the traverse on the 25 MB packed matrix is cheap
// (R3 == R2 despite totally different traverse structure). This version
// rebuilds the pack with: 16B/lane int4 loads (proven-fast width), pure
// per-lane ALU packing (no __ballot -> no per-256B vmcnt wait, no cross-lane
// op), and fully-coalesced full-wave stores (no 2-active-lane masked stores,
// no partial-sector writes). Output layout [blk][word][row&255] == what the
// traverse stages. Traverse keeps only the bit matrix in LDS (25.6 KB ->
// 6 blocks/CU); choices (256 KB) and preds (1 MB) stay L2-hot global.

#define WPR 25   // packed words per row (w=784)

// ---------------------------------------------------------------- pack v2
// Thread t of block b packs row b*256+t. 196 int4 loads, 25 words in regs,
// 25 coalesced stores. Layout: packed[b*WPR*256 + word*256 + t].
__global__ __launch_bounds__(256) void pack_kernel(
    const int* __restrict__ x,
    unsigned*  __restrict__ packed,
    int n)
{
    const int tid = threadIdx.x;
    const long long r = (long long)blockIdx.x * 256 + tid;
    if (r >= n) return;

    const int4* __restrict__ rowp = (const int4*)(x + r * 784LL); // 3136B, 16B-aligned
    unsigned acc[WPR];

    #pragma unroll 2
    for (int ww = 0; ww < 24; ++ww) {          // words 0..23: 8 int4 each
        unsigned a = 0;
        #pragma unroll
        for (int j = 0; j < 8; ++j) {
            const int4 v = rowp[(ww << 3) + j];  // feature 4*(8ww+j)+c
            a |= (unsigned)(v.x & 1) << ((j << 2) + 0);
            a |= (unsigned)(v.y & 1) << ((j << 2) + 1);
            a |= (unsigned)(v.z & 1) << ((j << 2) + 2);
            a |= (unsigned)(v.w & 1) << ((j << 2) + 3);
        }
        acc[ww] = a;
    }
    {   // word 24: features 768..783 (int4s 192..195), upper 16 bits zero
        unsigned a = 0;
        #pragma unroll
        for (int j = 0; j < 4; ++j) {
            const int4 v = rowp[192 + j];
            a |= (unsigned)(v.x & 1) << ((j << 2) + 0);
            a |= (unsigned)(v.y & 1) << ((j << 2) + 1);
            a |= (unsigned)(v.z & 1) << ((j << 2) + 2);
            a |= (unsigned)(v.w & 1) << ((j << 2) + 3);
        }
        acc[24] = a;
    }

    unsigned* __restrict__ outp = packed + (long long)blockIdx.x * (WPR * 256);
    #pragma unroll
    for (int ww = 0; ww < WPR; ++ww)
        outp[ww * 256 + tid] = acc[ww];        // full-wave coalesced (1KB/instr)
}

// ---------------------------------------------------------------- traverse
__global__ __launch_bounds__(256) void traverse_kernel(
    const unsigned* __restrict__ packed,
    const int*      __restrict__ choices,
    const float*    __restrict__ preds,
    const int*      __restrict__ depth_p,
    int* __restrict__ out, int n)
{
    __shared__ unsigned bits[WPR * 256];       // 25.6 KB -> 6 blocks/CU

    const int tid = threadIdx.x;
    const unsigned* __restrict__ src = packed + (long long)blockIdx.x * (WPR * 256);
    #pragma unroll
    for (int k = 0; k < WPR; ++k)
        bits[k * 256 + tid] = src[k * 256 + tid];   // coalesced, conflict-free
    __syncthreads();

    const long long i = (long long)blockIdx.x * 256 + tid;
    if (i >= n) return;

    const int depth = *depth_p;
    int node = 0;
    for (int d = 0; d < depth; ++d) {
        const int c = choices[node];                 // 256 KB table, L1/L2-hot
        const unsigned wv = bits[(c >> 5) * 256 + tid];  // bank = tid&31
        node = (node << 1) + (int)((wv >> (c & 31)) & 1u) + 1;
    }
    out[i] = (preds[node] != 0.0f) ? 1 : 0;
}

// ------------------------------------------------ fallback (baseline 911us)
__global__ __launch_bounds__(256) void direct_kernel(
    const int*   __restrict__ x,
    const int*   __restrict__ choices,
    const float* __restrict__ preds,
    const int*   __restrict__ depth_p,
    int*         __restrict__ out,
    int n, int w)
{
    const int i = blockIdx.x * blockDim.x + threadIdx.x;
    if (i >= n) return;
    const int depth = *depth_p;
    const int* __restrict__ row = x + (long long)i * (long long)w;
    int node = 0;
    for (int d = 0; d < depth; ++d) {
        const int c   = choices[node];
        const int bit = row[c];
        node = node * 2 + bit + 1;
    }
    out[i] = (preds[node] != 0.0f) ? 1 : 0;
}

extern "C" void kernel_launch(void* const* d_in, const int* in_sizes, int n_in,
                              void* d_out, int out_size, void* d_ws, size_t ws_size,
                              hipStream_t stream) {
    const int*   x       = (const int*)d_in[0];
    const int*   choices = (const int*)d_in[1];
    const float* preds   = (const float*)d_in[2];
    const int*   depth_p = (const int*)d_in[3];
    int*         out     = (int*)d_out;

    const int n = out_size;                 // 250000 samples
    const int w = in_sizes[0] / n;          // 784 features

    const long long nblk = (n + 255) / 256; // 977
    const size_t need = (size_t)nblk * WPR * 256 * sizeof(unsigned); // ~25 MB

    if (w != 784 || ws_size < need) {
        const int block = 256;
        const int grid  = (n + block - 1) / block;
        direct_kernel<<<grid, block, 0, stream>>>(x, choices, preds, depth_p,
                                                  out, n, w);
        return;
    }

    unsigned* packed = (unsigned*)d_ws;

    pack_kernel<<<dim3((unsigned)nblk), 256, 0, stream>>>(x, packed, n);
    traverse_kernel<<<dim3((unsigned)nblk), 256, 0, stream>>>(
        packed, choices, preds, depth_p, out, n);
}

// Round 5
// 1012.230 us; speedup vs baseline: 1.0720x; 1.0285x over previous
//
#include <hip/hip_runtime.h>

// Decision-tree traversal — single fused kernel, no workspace.
//
// x:      [N, W] int32 in {0,1}  (N=250000, W=784 -> 784 MB)
// choices:[N_NODES=65537] int32 split feature per node (values < 784)
// preds:  [N_NODES] float32 leaf prediction (0.0/1.0)
// depth:  scalar int32 on device (=15)
// out:    [N] int32 (bool 0/1)
//
// Series evidence (kernel-only = dur_us minus the ~490us ws-poison fill the
// harness runs inside the timed region; 3.136GB fill @6.35TB/s proves the
// context can stream at peak):
//   R0 direct gathers            = 421 us
//   R2/R3/R4 pack->ws->traverse  = 551..595 us (pack ~500, traverse ~30)
// This round: drop the ws round-trip entirely. Each thread packs its own row
// (196 int4 loads, pure ALU) into a PRIVATE LDS column (word-major [25][256],
// bank = tid&31 -> 2-way, free) and immediately traverses from LDS. No
// __syncthreads anywhere (threads only touch their own column), no second
// kernel, no 50 MB of ws traffic, no poison interaction. If this lands
// ~150-250us the ws path was the tax; if it stays ~500 the per-thread-row
// read pattern is convicted and next round coalesces the reads.

#define WPR 25   // packed words per row (w=784)

__global__ __launch_bounds__(256) void fused_kernel(
    const int*   __restrict__ x,
    const int*   __restrict__ choices,
    const float* __restrict__ preds,
    const int*   __restrict__ depth_p,
    int*         __restrict__ out,
    int n)
{
    __shared__ unsigned bits[WPR * 256];      // 25.6 KB -> 6 blocks/CU

    const int tid = threadIdx.x;
    const long long r = (long long)blockIdx.x * 256 + tid;
    if (r >= n) return;                       // safe: no barriers below

    const int4* __restrict__ rowp = (const int4*)(x + r * 784LL); // 16B-aligned

    // ---- pack own row: 784 features -> 25 words -> private LDS column ----
    #pragma unroll 2
    for (int ww = 0; ww < 24; ++ww) {         // words 0..23: 8 int4 each
        unsigned a = 0;
        #pragma unroll
        for (int j = 0; j < 8; ++j) {
            const int4 v = rowp[(ww << 3) + j];
            a |= (unsigned)(v.x & 1) << ((j << 2) + 0);
            a |= (unsigned)(v.y & 1) << ((j << 2) + 1);
            a |= (unsigned)(v.z & 1) << ((j << 2) + 2);
            a |= (unsigned)(v.w & 1) << ((j << 2) + 3);
        }
        bits[ww * 256 + tid] = a;
    }
    {   // word 24: features 768..783
        unsigned a = 0;
        #pragma unroll
        for (int j = 0; j < 4; ++j) {
            const int4 v = rowp[192 + j];
            a |= (unsigned)(v.x & 1) << ((j << 2) + 0);
            a |= (unsigned)(v.y & 1) << ((j << 2) + 1);
            a |= (unsigned)(v.z & 1) << ((j << 2) + 2);
            a |= (unsigned)(v.w & 1) << ((j << 2) + 3);
        }
        bits[24 * 256 + tid] = a;
    }

    // ---- traverse from own LDS column (no sync needed) ----
    const int depth = *depth_p;               // uniform scalar (=15)
    int node = 0;
    for (int d = 0; d < depth; ++d) {
        const int c = choices[node];          // 256 KB table, L1/L2-hot
        const unsigned wv = bits[(c >> 5) * 256 + tid];   // bank = tid&31
        node = (node << 1) + (int)((wv >> (c & 31)) & 1u) + 1;
    }
    out[r] = (preds[node] != 0.0f) ? 1 : 0;   // bool as int32
}

// ------------------------------------------------ fallback for generic w
__global__ __launch_bounds__(256) void direct_kernel(
    const int*   __restrict__ x,
    const int*   __restrict__ choices,
    const float* __restrict__ preds,
    const int*   __restrict__ depth_p,
    int*         __restrict__ out,
    int n, int w)
{
    const int i = blockIdx.x * blockDim.x + threadIdx.x;
    if (i >= n) return;
    const int depth = *depth_p;
    const int* __restrict__ row = x + (long long)i * (long long)w;
    int node = 0;
    for (int d = 0; d < depth; ++d) {
        const int c   = choices[node];
        const int bit = row[c];
        node = node * 2 + bit + 1;
    }
    out[i] = (preds[node] != 0.0f) ? 1 : 0;
}

extern "C" void kernel_launch(void* const* d_in, const int* in_sizes, int n_in,
                              void* d_out, int out_size, void* d_ws, size_t ws_size,
                              hipStream_t stream) {
    const int*   x       = (const int*)d_in[0];
    const int*   choices = (const int*)d_in[1];
    const float* preds   = (const float*)d_in[2];
    const int*   depth_p = (const int*)d_in[3];
    int*         out     = (int*)d_out;

    const int n = out_size;                 // 250000 samples
    const int w = in_sizes[0] / n;          // 784 features

    const int block = 256;
    const int grid  = (n + block - 1) / block;   // 977 blocks

    if (w == 784) {
        fused_kernel<<<grid, block, 0, stream>>>(x, choices, preds, depth_p,
                                                 out, n);
    } else {
        direct_kernel<<<grid, block, 0, stream>>>(x, choices, preds, depth_p,
                                                  out, n, w);
    }
}

// Round 6
// 978.252 us; speedup vs baseline: 1.1092x; 1.0347x over previous
//
#include <hip/hip_runtime.h>

// Decision-tree traversal — fused, wave-cooperative coalesced pack + LDS traverse.
//
// x:      [N, W] int32 in {0,1}  (N=250000, W=784 -> 784 MB)
// choices:[N_NODES=65537] int32 split feature per node (values < 784)
// preds:  [N_NODES] float32 leaf prediction (0.0/1.0)
// depth:  scalar int32 on device (=15)
// out:    [N] int32 (bool 0/1)
//
// Series attribution (kernel-only = dur_us - ~490us ws-poison fill):
//   R0 direct dependent gathers          = 421 us  (DRAM-page-miss bound)
//   R4/R5 per-thread-row int4 pack       = ~520 us (64 lines/instr, L1/L2
//         live-set 196KB/CU & 6.3MB/XCD -> ~4x line refetch => 1.5 TB/s)
//   R2/R3 ballot pack                    = ~570 us (vmcnt drain per 256B load)
// This version: a wave reads ONE row cooperatively (lane L takes int4
// {L, 64+L, 128+L} + 4-int4 tail) -> every load is a contiguous 1KB segment
// (the idiom the poison fill proves runs at 6.35 TB/s here). 4 rows' loads
// (16, independent) issue before any ballot -> one HBM latency per group.
// Ballots transpose 64 features/word-pair; bit layout is "scrambled" but the
// traverse applies the matching c -> (word,bit) mapping. Bits in LDS [28][256]
// (28.7 KB -> 5 blocks/CU LDS-wise; bank = tid&31 -> conflict-free). Each wave
// writes and reads only its own 64 columns: NO __syncthreads anywhere.

#define WPR 28   // 24 full words + 4 tail words per row

__global__ __launch_bounds__(256) void fused_kernel(
    const int*   __restrict__ x,
    const int*   __restrict__ choices,
    const float* __restrict__ preds,
    const int*   __restrict__ depth_p,
    int*         __restrict__ out,
    int n)
{
    __shared__ unsigned bits[WPR * 256];   // [word][col], col = block-local row

    const int tid  = threadIdx.x;
    const int lane = tid & 63;
    const int wid  = tid >> 6;                        // wave in block
    const long long base = (long long)blockIdx.x * 256;

    // ---- pack: wave wid packs block-local rows [wid*64, wid*64+64) ----
    for (int it = 0; it < 16; ++it) {                 // 4 rows per iteration
        const int r0 = (wid << 6) + (it << 2);        // block-local row of group

        // 16 independent coalesced loads (12x 1KB + 4x 64B tail), all in
        // flight before the first ballot consumes any of them.
        int4 v0[4], v1[4], v2[4], v3[4];
        #pragma unroll
        for (int rr = 0; rr < 4; ++rr) {
            long long gr = base + r0 + rr;
            if (gr >= n) gr = n - 1;                  // clamp (tail block)
            const int4* __restrict__ rowp = (const int4*)(x + gr * 784LL);
            v0[rr] = rowp[lane];                      // features 4*lane + c
            v1[rr] = rowp[64 + lane];
            v2[rr] = rowp[128 + lane];
            v3[rr] = rowp[192 + (lane & 3)];          // tail: 1 line, 4 addrs
        }

        #pragma unroll
        for (int rr = 0; rr < 4; ++rr) {
            const int col = r0 + rr;
            unsigned long long m[12];                 // static-indexed only
            #pragma unroll
            for (int cmp = 0; cmp < 4; ++cmp) {
                m[0 + cmp] = __ballot(((&v0[rr].x)[cmp] & 1) != 0);
                m[4 + cmp] = __ballot(((&v1[rr].x)[cmp] & 1) != 0);
                m[8 + cmp] = __ballot(((&v2[rr].x)[cmp] & 1) != 0);
            }
            unsigned long long t[4];
            #pragma unroll
            for (int cmp = 0; cmp < 4; ++cmp)
                t[cmp] = __ballot(((&v3[rr].x)[cmp] & 1) != 0);

            if (lane < 2) {                           // 2 lanes store halves
                #pragma unroll
                for (int q = 0; q < 12; ++q) {
                    const int w = ((q >> 2) << 3) + ((q & 3) << 1) + lane;
                    bits[w * 256 + col] = (unsigned)(m[q] >> (lane << 5));
                }
            }
            if (lane == 0) {
                #pragma unroll
                for (int cmp = 0; cmp < 4; ++cmp)
                    bits[(24 + cmp) * 256 + col] = (unsigned)t[cmp];
            }
        }
    }
    // no __syncthreads: each wave traverses only columns it wrote itself

    // ---- traverse own row from LDS ----
    const long long i = base + tid;
    if (i >= n) return;

    const int depth = *depth_p;                       // uniform scalar (=15)
    int node = 0;
    for (int d = 0; d < depth; ++d) {
        const int c  = choices[node];                 // 256 KB table, L2-hot
        // scrambled-layout mapping: word/bit for feature c
        int w;
        if (c < 768) w = ((c >> 8) << 3) | ((c & 3) << 1) | ((c >> 7) & 1);
        else         w = 24 | (c & 3);
        const unsigned wv = bits[w * 256 + tid];      // bank = tid&31, free
        node = (node << 1) + (int)((wv >> ((c >> 2) & 31)) & 1u) + 1;
    }
    out[i] = (preds[node] != 0.0f) ? 1 : 0;           // bool as int32
}

// ------------------------------------------------ fallback for generic w
__global__ __launch_bounds__(256) void direct_kernel(
    const int*   __restrict__ x,
    const int*   __restrict__ choices,
    const float* __restrict__ preds,
    const int*   __restrict__ depth_p,
    int*         __restrict__ out,
    int n, int w)
{
    const int i = blockIdx.x * blockDim.x + threadIdx.x;
    if (i >= n) return;
    const int depth = *depth_p;
    const int* __restrict__ row = x + (long long)i * (long long)w;
    int node = 0;
    for (int d = 0; d < depth; ++d) {
        const int c   = choices[node];
        const int bit = row[c];
        node = node * 2 + bit + 1;
    }
    out[i] = (preds[node] != 0.0f) ? 1 : 0;
}

extern "C" void kernel_launch(void* const* d_in, const int* in_sizes, int n_in,
                              void* d_out, int out_size, void* d_ws, size_t ws_size,
                              hipStream_t stream) {
    const int*   x       = (const int*)d_in[0];
    const int*   choices = (const int*)d_in[1];
    const float* preds   = (const float*)d_in[2];
    const int*   depth_p = (const int*)d_in[3];
    int*         out     = (int*)d_out;

    const int n = out_size;                 // 250000 samples
    const int w = in_sizes[0] / n;          // 784 features

    const int block = 256;
    const int grid  = (n + block - 1) / block;   // 977 blocks

    if (w == 784) {
        fused_kernel<<<grid, block, 0, stream>>>(x, choices, preds, depth_p,
                                                 out, n);
    } else {
        direct_kernel<<<grid, block, 0, stream>>>(x, choices, preds, depth_p,
                                                  out, n, w);
    }
}